// Round 1
// 1158.700 us; speedup vs baseline: 1.1464x; 1.1464x over previous
//
#include <hip/hip_runtime.h>
#include <cmath>

// Problem constants
#define M_MOD 8
#define BATCH 4096
#define DIM   512
#define NPAIR 56
static const size_t BD = (size_t)BATCH * DIM;   // 2,097,152

typedef __attribute__((ext_vector_type(8))) short  short8;   // 8 bf16 = 4 VGPRs
typedef __attribute__((ext_vector_type(4))) float  floatx4;

// ---- d_out layout (float offsets)
#define OFF_FUSED   0UL
#define OFF_UNIFIED 16777216UL
#define OFF_ATTNW   18874368UL
#define OFF_ATT     19103744UL
#define OFF_IMP     136544256UL
#define OFF_HEAT    136577024UL

// ---- workspace layout (BYTE offsets). Total need = 181,649,408 B (~182 MB).
// comb_bf (M,B,1024) bf16: cols 0:512 = modal_embs, cols 512:1024 = cross
#define WB_COMB   0UL
// U1: phase1 = opw_bf(29.3MB)+wvT_bf(29.3MB); phase2 (after k_wc) = h1_bf+fused_bf
#define WB_U1     67108864UL
#define WB_OPW    (WB_U1)
#define WB_WVT    (WB_U1 + 29360128UL)
#define WB_H1     (WB_U1)
#define WB_FUSEDB (WB_U1 + 33554432UL)
// U2: Wc_bf (29.3MB); after k_att_cross reused for t1 (8.4MB fp32)
#define WB_U2     134217728UL
// U3: small persistents
#define WB_F1W    163577856UL
#define WB_F2W    (WB_F1W + 8388608UL)
#define WB_C1W    (WB_F2W + 4194304UL)
#define WB_RQ     (WB_C1W + 1048576UL)
#define WB_GACC   (WB_RQ  + 4194304UL)
#define WB_BC     (WB_GACC + 131072UL)

// ---------------------------------------------------------------------------
__device__ __forceinline__ unsigned short f2b_bits(float f) {
    unsigned int u = __float_as_uint(f);
    unsigned int r = (u + 0x7fffu + ((u >> 16) & 1u)) >> 16;   // RNE
    return (unsigned short)r;
}

__device__ __forceinline__ void gload16(const unsigned short* g, short* l) {
    __builtin_amdgcn_global_load_lds((const __attribute__((address_space(1))) void*)g,
                                     (__attribute__((address_space(3))) void*)l,
                                     16, 0, 0);
}

// ---------------------------------------------------------------------------
// bf16 MFMA NT GEMM: C[z][i][j] = sum_k A[z][i][k] * B[z][j][k]
// 128x128 tile, 4 waves (2x2), each wave 4x4 of 16x16x32 MFMA, BK=32.
// EPI: 0 = bf16 out (no bias)         [Wc]
//      1 = fp32 out + bias            [t1]
//      2 = relu(acc+bias) -> bf16     [h1]
//      3 = acc+bias -> fp32 AND bf16  [fused]
//      4 = gate reduction -> atomicAdd gacc   [h2/gate]
// All grids have nwg % 8 == 0 -> bijective XCD swizzle (T1) applies.
// ---------------------------------------------------------------------------
template<int EPI>
__global__ __launch_bounds__(256)
void k_mm(const unsigned short* __restrict__ A, long long az, int lda,
          const unsigned short* __restrict__ B, long long bz, int ldb,
          const float* __restrict__ bias, int biasz,
          float* __restrict__ Cf, long long cfz,
          unsigned short* __restrict__ Cb, long long cbz,
          const float* __restrict__ t1, const float* __restrict__ c2w,
          float* __restrict__ gacc, int K)
{
    // ---- XCD-aware bijective block swizzle (nwg divisible by 8 for all calls)
    const int gx = gridDim.x, gy = gridDim.y;
    const int nwg = gx * gy * (int)gridDim.z;
    int bid = blockIdx.x + gx * (blockIdx.y + gy * blockIdx.z);
    bid = (bid & 7) * (nwg >> 3) + (bid >> 3);
    const int bxi = bid % gx; int tq = bid / gx;
    const int byi = tq % gy;
    const int z   = tq / gy;

    const unsigned short* Ab = A + (size_t)z * az;
    const unsigned short* Bb = B + (size_t)z * bz;
    const int row0 = byi * 128, col0 = bxi * 128;

    __shared__ short As[128 * 32];   // [row][k], 64 B per row
    __shared__ short Bs[128 * 32];   // [col][k]

    const int tid = threadIdx.x, w = tid >> 6, lane = tid & 63;
    // staging: wave w fills rows 32w..32w+31 of As and Bs (two 16-row chunks)
    const int srow = 32 * w + (lane >> 2);
    const int skq  = (lane & 3) * 8;
    const unsigned short* ga = Ab + (size_t)(row0 + srow) * lda + skq;
    const unsigned short* gb = Bb + (size_t)(col0 + srow) * ldb + skq;
    short* lA = As + 1024 * w;
    short* lB = Bs + 1024 * w;

    const int tg = lane >> 4, tm = lane & 15;          // frag indices
    const int wr = (w >> 1) * 64, wc = (w & 1) * 64;   // wave tile origin

    floatx4 acc[4][4];
    const floatx4 zero4 = {0.f, 0.f, 0.f, 0.f};
#pragma unroll
    for (int i = 0; i < 4; ++i)
#pragma unroll
        for (int j = 0; j < 4; ++j) acc[i][j] = zero4;

    for (int k0 = 0; k0 < K; k0 += 32) {
        gload16(ga + k0,                    lA);
        gload16(ga + k0 + (size_t)16 * lda, lA + 512);
        gload16(gb + k0,                    lB);
        gload16(gb + k0 + (size_t)16 * ldb, lB + 512);
        __syncthreads();   // drains own vmcnt before barrier
        short8 av[4], bv[4];
#pragma unroll
        for (int i = 0; i < 4; ++i)
            av[i] = *(const short8*)(As + (wr + i * 16 + tm) * 32 + tg * 8);
#pragma unroll
        for (int j = 0; j < 4; ++j)
            bv[j] = *(const short8*)(Bs + (wc + j * 16 + tm) * 32 + tg * 8);
#pragma unroll
        for (int i = 0; i < 4; ++i)
#pragma unroll
            for (int j = 0; j < 4; ++j)
                acc[i][j] = __builtin_amdgcn_mfma_f32_16x16x32_bf16(av[i], bv[j], acc[i][j], 0, 0, 0);
        __syncthreads();   // all waves done reading before next overwrite
    }

    // ---- epilogue. C/D layout: col = lane&15, row = (lane>>4)*4 + reg
    const int gc0 = col0 + wc + tm;
    const int gr0 = row0 + wr + tg * 4;

    if (EPI == 4) {
#pragma unroll
        for (int i = 0; i < 4; ++i)
#pragma unroll
            for (int reg = 0; reg < 4; ++reg) {
                const int r = gr0 + i * 16 + reg;
                float s = 0.f;
#pragma unroll
                for (int j = 0; j < 4; ++j) {
                    const int c = gc0 + j * 16;
                    float h = fmaxf(acc[i][j][reg] + t1[(size_t)r * DIM + c], 0.f);
                    s = fmaf(h, c2w[c], s);
                }
                s += __shfl_xor(s, 8); s += __shfl_xor(s, 4);
                s += __shfl_xor(s, 2); s += __shfl_xor(s, 1);
                if (tm == 0) atomicAdd(gacc + (size_t)z * BATCH + r, s);
            }
    } else {
        float bb[4] = {0.f, 0.f, 0.f, 0.f};
        if (EPI == 1 || EPI == 2 || EPI == 3) {
#pragma unroll
            for (int j = 0; j < 4; ++j) bb[j] = bias[(size_t)z * biasz + gc0 + j * 16];
        }
#pragma unroll
        for (int i = 0; i < 4; ++i)
#pragma unroll
            for (int reg = 0; reg < 4; ++reg) {
                const size_t rbase = (size_t)(gr0 + i * 16 + reg) * DIM;
#pragma unroll
                for (int j = 0; j < 4; ++j) {
                    const int c = gc0 + j * 16;
                    float v = acc[i][j][reg] + bb[j];
                    if (EPI == 2) v = fmaxf(v, 0.f);
                    if (EPI == 0 || EPI == 2 || EPI == 3)
                        Cb[(size_t)z * cbz + rbase + c] = f2b_bits(v);
                    if (EPI == 1 || EPI == 3)
                        Cf[(size_t)z * cfz + rbase + c] = v;
                }
            }
    }
}

// ---------------------------------------------------------------------------
// Fused attended + cross: grid (4, 32, 8). For block (bx,by,m) loop j=0..6:
// full K=512 GEMM for pair p=m*7+j, write attended[p] tile (fp32, mandatory
// output), accumulate fp32 cross sum in registers. End: write cross/7 as bf16
// into comb cols 512:1024. Eliminates the 470 MB k_cross re-read.
// ---------------------------------------------------------------------------
__global__ __launch_bounds__(256, 2)
void k_att_cross(unsigned short* comb,                    // A src + cross dst
                 const unsigned short* __restrict__ wcb,  // (P,512,512) bf16
                 const float* __restrict__ bcv,           // (P,512)
                 float* __restrict__ att)                 // (P,B,512) fp32
{
    // bijective XCD swizzle, nwg = 1024
    int bid = blockIdx.x + 4 * (blockIdx.y + 32 * blockIdx.z);
    bid = (bid & 7) * 128 + (bid >> 3);
    const int bxi = bid & 3, byi = (bid >> 2) & 31, m = bid >> 7;
    const int row0 = byi * 128, col0 = bxi * 128;

    __shared__ short As[128 * 32];
    __shared__ short Bs[128 * 32];

    const int tid = threadIdx.x, w = tid >> 6, lane = tid & 63;
    const int srow = 32 * w + (lane >> 2);
    const int skq  = (lane & 3) * 8;
    short* lA = As + 1024 * w;
    short* lB = Bs + 1024 * w;
    const int tg = lane >> 4, tm = lane & 15;
    const int wr = (w >> 1) * 64, wc = (w & 1) * 64;

    const int gc0 = col0 + wc + tm;
    const int gr0 = row0 + wr + tg * 4;

    const floatx4 zero4 = {0.f, 0.f, 0.f, 0.f};
    floatx4 accc[4][4];
#pragma unroll
    for (int i = 0; i < 4; ++i)
#pragma unroll
        for (int j = 0; j < 4; ++j) accc[i][j] = zero4;

    for (int jj = 0; jj < 7; ++jj) {
        const int za = jj + (jj >= m ? 1 : 0);
        const int p  = m * 7 + jj;
        const unsigned short* ga = comb + (size_t)za * BATCH * 1024
                                        + (size_t)(row0 + srow) * 1024 + skq;
        const unsigned short* gb = wcb + (size_t)p * DIM * DIM
                                       + (size_t)(col0 + srow) * DIM + skq;
        floatx4 acc[4][4];
#pragma unroll
        for (int i = 0; i < 4; ++i)
#pragma unroll
            for (int j = 0; j < 4; ++j) acc[i][j] = zero4;

        for (int k0 = 0; k0 < DIM; k0 += 32) {
            gload16(ga + k0,              lA);
            gload16(ga + k0 + 16 * 1024,  lA + 512);
            gload16(gb + k0,              lB);
            gload16(gb + k0 + 16 * DIM,   lB + 512);
            __syncthreads();
            short8 av[4], bv[4];
#pragma unroll
            for (int i = 0; i < 4; ++i)
                av[i] = *(const short8*)(As + (wr + i * 16 + tm) * 32 + tg * 8);
#pragma unroll
            for (int j = 0; j < 4; ++j)
                bv[j] = *(const short8*)(Bs + (wc + j * 16 + tm) * 32 + tg * 8);
#pragma unroll
            for (int i = 0; i < 4; ++i)
#pragma unroll
                for (int j = 0; j < 4; ++j)
                    acc[i][j] = __builtin_amdgcn_mfma_f32_16x16x32_bf16(av[i], bv[j], acc[i][j], 0, 0, 0);
            __syncthreads();
        }

        // epilogue for pair p: bias, store attended fp32, accumulate cross
        float bb[4];
#pragma unroll
        for (int j = 0; j < 4; ++j) bb[j] = bcv[(size_t)p * DIM + gc0 + j * 16];
        float* ab = att + (size_t)p * BD;
#pragma unroll
        for (int i = 0; i < 4; ++i)
#pragma unroll
            for (int reg = 0; reg < 4; ++reg) {
                const size_t rbase = (size_t)(gr0 + i * 16 + reg) * DIM;
#pragma unroll
                for (int j = 0; j < 4; ++j) {
                    float v = acc[i][j][reg] + bb[j];
                    ab[rbase + gc0 + j * 16] = v;
                    accc[i][j][reg] += v;
                }
            }
    }

    // cross = accc/7 -> comb cols 512:1024 (bf16)
    const float c7 = 1.f / 7.f;
#pragma unroll
    for (int i = 0; i < 4; ++i)
#pragma unroll
        for (int reg = 0; reg < 4; ++reg) {
            const size_t rbase = ((size_t)(m * BATCH + gr0 + i * 16 + reg)) * 1024 + 512;
#pragma unroll
            for (int j = 0; j < 4; ++j)
                comb[rbase + gc0 + j * 16] = f2b_bits(accc[i][j][reg] * c7);
        }
}

// ---------------------------------------------------------------------------
// Conversion kernels
// ---------------------------------------------------------------------------
__global__ void k_f2b(const float* __restrict__ in, unsigned short* __restrict__ out, int n4)
{
    int i = blockIdx.x * 256 + threadIdx.x;
    if (i >= n4) return;
    float4 v = ((const float4*)in)[i];
    ushort4 o;
    o.x = f2b_bits(v.x); o.y = f2b_bits(v.y); o.z = f2b_bits(v.z); o.w = f2b_bits(v.w);
    *(ushort4*)(out + (size_t)i * 4) = o;
}

// modal_embs -> comb_bf cols 0:512 (ld 1024), fused with importance (row norms)
__global__ void k_me2comb(const float* __restrict__ me, unsigned short* __restrict__ comb,
                          float* __restrict__ imp)
{
    __shared__ float red[256];
    int gid = blockIdx.x * 256 + threadIdx.x;          // < M*B*128
    int row = gid >> 7;                                 // mb index (m*4096+b)
    int dq  = (gid & 127) * 4;
    float4 v = *(const float4*)(me + (size_t)row * 512 + dq);
    ushort4 o;
    o.x = f2b_bits(v.x); o.y = f2b_bits(v.y); o.z = f2b_bits(v.z); o.w = f2b_bits(v.w);
    *(ushort4*)(comb + (size_t)row * 1024 + dq) = o;
    red[threadIdx.x] = v.x * v.x + v.y * v.y + v.z * v.z + v.w * v.w;
    __syncthreads();
#pragma unroll
    for (int s = 64; s >= 1; s >>= 1) {
        if ((threadIdx.x & 127) < s) red[threadIdx.x] += red[threadIdx.x + s];
        __syncthreads();
    }
    if ((threadIdx.x & 127) == 0) {
        // imp layout (B, M): imp[b*8 + m]; row = m*4096 + b
        imp[(size_t)(row & 4095) * 8 + (row >> 12)] = sqrtf(red[threadIdx.x]);
    }
}

// Wv transpose-convert: wvT[p][d][f] = ipw[p][2D+f][d]
__global__ void k_wvT(const float* __restrict__ ipw, unsigned short* __restrict__ wvT)
{
    __shared__ float t[32][33];
    const int p = blockIdx.z;
    const float* src = ipw + (size_t)p * 3 * DIM * DIM + (size_t)2 * DIM * DIM;
    const int d0 = blockIdx.x * 32, f0 = blockIdx.y * 32;
    for (int r = threadIdx.y; r < 32; r += 8)
        t[r][threadIdx.x] = src[(size_t)(f0 + r) * DIM + d0 + threadIdx.x];
    __syncthreads();
    unsigned short* dst = wvT + (size_t)p * DIM * DIM;
    for (int r = threadIdx.y; r < 32; r += 8)
        dst[(size_t)(d0 + r) * DIM + f0 + threadIdx.x] = f2b_bits(t[threadIdx.x][r]);
}

// bc[p][e] = sum_f Wo[p][e][f]*bv[p][f] + bo[p][e]   (fp32, tiny)
// grid (8, 56): 4 lanes per output row + shuffle reduce (was 56 blocks -> BW-starved)
__global__ void k_bc(const float* __restrict__ opw, const float* __restrict__ ipb,
                     const float* __restrict__ opb, float* __restrict__ bc)
{
    const int p = blockIdx.y;
    const int e = blockIdx.x * 64 + (threadIdx.x >> 2);
    const int part = threadIdx.x & 3;
    const float4* row = (const float4*)(opw + (size_t)p * DIM * DIM + (size_t)e * DIM) + part * 32;
    const float4* bv  = (const float4*)(ipb + (size_t)p * 3 * DIM + 2 * DIM) + part * 32;
    float s = 0.f;
#pragma unroll 4
    for (int f = 0; f < 32; ++f) {
        float4 a = row[f], b = bv[f];
        s += a.x * b.x + a.y * b.y + a.z * b.z + a.w * b.w;
    }
    s += __shfl_xor(s, 1); s += __shfl_xor(s, 2);
    if (part == 0) bc[(size_t)p * DIM + e] = s + opb[(size_t)p * DIM + e];
}

// unified[b][d] = (1/M) * sum_m fused[m][b][d] * sigmoid(gacc[m][b] + c2b)
__global__ void k_unified(const float* __restrict__ fused, const float* __restrict__ gacc,
                          const float* __restrict__ c2b, float* __restrict__ uni)
{
    const size_t idx = (size_t)blockIdx.x * 256 + threadIdx.x;   // < B*D/4
    const int b = (int)(idx >> 7);
    const float cb = c2b[0];
    float4 s = make_float4(0.f, 0.f, 0.f, 0.f);
#pragma unroll
    for (int m = 0; m < M_MOD; ++m) {
        float g = 1.f / (1.f + expf(-(gacc[(size_t)m * BATCH + b] + cb)));
        float4 f = ((const float4*)fused)[(size_t)m * (BD / 4) + idx];
        s.x = fmaf(f.x, g, s.x); s.y = fmaf(f.y, g, s.y);
        s.z = fmaf(f.z, g, s.z); s.w = fmaf(f.w, g, s.w);
    }
    const float c = 1.f / (float)M_MOD;
    ((float4*)uni)[idx] = make_float4(s.x * c, s.y * c, s.z * c, s.w * c);
}

__global__ void k_fill(float* __restrict__ out)
{
    const size_t gid = (size_t)blockIdx.x * 256 + threadIdx.x;
    if (gid < 229376UL) {
        out[OFF_ATTNW + gid] = 1.0f;
    } else if (gid < 229440UL) {
        const int r8 = (int)(gid - 229376UL);
        out[OFF_HEAT + r8] = ((r8 >> 3) == (r8 & 7)) ? 0.f : 1.f;
    }
}

// ---------------------------------------------------------------------------
extern "C" void kernel_launch(void* const* d_in, const int* in_sizes, int n_in,
                              void* d_out, int out_size, void* d_ws, size_t ws_size,
                              hipStream_t stream)
{
    const float* me  = (const float*)d_in[0];
    const float* rq  = (const float*)d_in[1];
    const float* ipw = (const float*)d_in[2];
    const float* ipb = (const float*)d_in[3];
    const float* opw = (const float*)d_in[4];
    const float* opb = (const float*)d_in[5];
    const float* f1w = (const float*)d_in[6];
    const float* f1b = (const float*)d_in[7];
    const float* f2w = (const float*)d_in[8];
    const float* f2b = (const float*)d_in[9];
    const float* c1w = (const float*)d_in[10];
    const float* c1b = (const float*)d_in[11];
    const float* c2w = (const float*)d_in[12];
    const float* c2b = (const float*)d_in[13];
    float* out = (float*)d_out;
    char*  wsb = (char*)d_ws;   // needs >= 181,649,408 bytes

    unsigned short* comb   = (unsigned short*)(wsb + WB_COMB);
    unsigned short* opw_bf = (unsigned short*)(wsb + WB_OPW);
    unsigned short* wvT_bf = (unsigned short*)(wsb + WB_WVT);
    unsigned short* h1_bf  = (unsigned short*)(wsb + WB_H1);
    unsigned short* fus_bf = (unsigned short*)(wsb + WB_FUSEDB);
    unsigned short* wc_bf  = (unsigned short*)(wsb + WB_U2);
    float*          t1     = (float*)(wsb + WB_U2);
    unsigned short* f1w_bf = (unsigned short*)(wsb + WB_F1W);
    unsigned short* f2w_bf = (unsigned short*)(wsb + WB_F2W);
    unsigned short* c1w_bf = (unsigned short*)(wsb + WB_C1W);
    unsigned short* rq_bf  = (unsigned short*)(wsb + WB_RQ);
    float*          gacc   = (float*)(wsb + WB_GACC);
    float*          bc     = (float*)(wsb + WB_BC);

    dim3 blk(256);

    // ---- conversions (k_bc right after opw conversion: opw L3-hot)
    k_f2b<<<dim3(14336), blk, 0, stream>>>(opw, opw_bf, 3670016);            // out_proj_w
    k_bc<<<dim3(8, NPAIR), blk, 0, stream>>>(opw, ipb, opb, bc);
    k_wvT<<<dim3(16, 16, NPAIR), dim3(32, 8), 0, stream>>>(ipw, wvT_bf);     // Wv^T
    k_f2b<<<dim3(4096),  blk, 0, stream>>>(f1w, f1w_bf, 1048576);
    k_f2b<<<dim3(2048),  blk, 0, stream>>>(f2w, f2w_bf, 524288);
    k_f2b<<<dim3(512),   blk, 0, stream>>>(c1w, c1w_bf, 131072);
    k_f2b<<<dim3(2048),  blk, 0, stream>>>(rq,  rq_bf,  524288);
    k_me2comb<<<dim3(16384), blk, 0, stream>>>(me, comb, out + OFF_IMP);
    hipMemsetAsync(gacc, 0, (size_t)M_MOD * BATCH * sizeof(float), stream);

    // ---- Wc[p] = Wo[p] @ Wv[p]   (bf16 out)
    k_mm<0><<<dim3(4, 4, NPAIR), blk, 0, stream>>>(
        opw_bf, (long long)DIM * DIM, DIM, wvT_bf, (long long)DIM * DIM, DIM,
        nullptr, 0, nullptr, 0, wc_bf, (long long)DIM * DIM,
        nullptr, nullptr, nullptr, DIM);

    // ---- attended[p] = me[tgt(p)] @ Wc[p]^T + bc  (fp32 to d_out)
    //      + cross = mean_j attended[m*7+j] fused in-register -> comb cols 512:1024
    k_att_cross<<<dim3(4, 32, M_MOD), blk, 0, stream>>>(comb, wc_bf, bc, out + OFF_ATT);

    // ---- t1 = rq @ c1w[:, :D]^T + c1b  (fp32; overlays dead Wc region)
    k_mm<1><<<dim3(4, 32, 1), blk, 0, stream>>>(
        rq_bf, 0, DIM, c1w_bf, 0, 1024,
        c1b, 0, t1, 0, nullptr, 0,
        nullptr, nullptr, nullptr, DIM);

    // ---- h1 = relu(comb @ f1w^T + f1b)  (K=1024, bf16 out)
    k_mm<2><<<dim3(4, 32, M_MOD), blk, 0, stream>>>(
        comb, (long long)BATCH * 1024, 1024, f1w_bf, (long long)DIM * 1024, 1024,
        f1b, DIM, nullptr, 0, h1_bf, (long long)BD,
        nullptr, nullptr, nullptr, 1024);

    // ---- fused = h1 @ f2w^T + f2b  (fp32 to d_out + bf16 copy)
    k_mm<3><<<dim3(4, 32, M_MOD), blk, 0, stream>>>(
        h1_bf, (long long)BD, DIM, f2w_bf, (long long)DIM * DIM, DIM,
        f2b, DIM, out + OFF_FUSED, (long long)BD, fus_bf, (long long)BD,
        nullptr, nullptr, nullptr, DIM);

    // ---- gate: gacc += sum_e relu(fused @ c1w[:,D:]^T + t1) * c2w
    k_mm<4><<<dim3(4, 32, M_MOD), blk, 0, stream>>>(
        fus_bf, (long long)BD, DIM, c1w_bf + 512, 0, 1024,
        nullptr, 0, nullptr, 0, nullptr, 0,
        t1, c2w, gacc, DIM);

    // ---- epilogue kernels
    k_unified<<<dim3(2048), blk, 0, stream>>>(out + OFF_FUSED, gacc, c2b, out + OFF_UNIFIED);
    k_fill<<<dim3(897), blk, 0, stream>>>(out);
}